// Round 1
// 580.970 us; speedup vs baseline: 1.2422x; 1.2422x over previous
//
#include <hip/hip_runtime.h>
#include <hip/hip_bf16.h>

typedef __hip_bfloat16 bf16;
typedef __attribute__((ext_vector_type(8))) short short8;
typedef __attribute__((ext_vector_type(4))) float float4v;

static __device__ __forceinline__ float b2f(bf16 x) { return __bfloat162float(x); }

// dtype-dispatched load/store: f32=1 -> buffer is float32, f32=0 -> bfloat16.
static __device__ __forceinline__ float ldf(const void* p, size_t i, int f32) {
    return f32 ? ((const float*)p)[i] : b2f(((const bf16*)p)[i]);
}
static __device__ __forceinline__ void stf(void* p, size_t i, int f32, float v) {
    if (f32) ((float*)p)[i] = v;
    else     ((bf16*)p)[i] = __float2bfloat16(v);
}
static __device__ __forceinline__ unsigned short f2bf_bits(float f) {
    bf16 h = __float2bfloat16(f);
    return *(unsigned short*)&h;
}

// fast tanh: 1 - 2/(e^2x + 1)
static __device__ __forceinline__ float fast_tanh(float x) {
    float t = __expf(2.f * x);
    return 1.f - 2.f * __builtin_amdgcn_rcpf(t + 1.f);
}

// load 16 edge-attr channels of edge e into registers (either dtype)
static __device__ __forceinline__ void load_ea16(const void* ea, size_t e, int f32, float* er) {
    if (f32) {
        const float4* p = (const float4*)((const float*)ea + e * 16);
        #pragma unroll
        for (int q = 0; q < 4; ++q) {
            float4 v = p[q];
            er[4*q] = v.x; er[4*q+1] = v.y; er[4*q+2] = v.z; er[4*q+3] = v.w;
        }
    } else {
        const uint4* p = (const uint4*)((const bf16*)ea + e * 16);
        #pragma unroll
        for (int q = 0; q < 2; ++q) {
            uint4 u = p[q];
            er[8*q+0] = __uint_as_float(u.x << 16);
            er[8*q+1] = __uint_as_float(u.x & 0xffff0000u);
            er[8*q+2] = __uint_as_float(u.y << 16);
            er[8*q+3] = __uint_as_float(u.y & 0xffff0000u);
            er[8*q+4] = __uint_as_float(u.z << 16);
            er[8*q+5] = __uint_as_float(u.z & 0xffff0000u);
            er[8*q+6] = __uint_as_float(u.w << 16);
            er[8*q+7] = __uint_as_float(u.w & 0xffff0000u);
        }
    }
}

// ---------------- dtype detector ----------------
__global__ void detect_kernel(const unsigned short* __restrict__ a, int* __restrict__ flag)
{
    __shared__ int cnt;
    if (threadIdx.x == 0) cnt = 0;
    __syncthreads();
    unsigned e = (a[threadIdx.x] >> 7) & 0xFF;
    if (e < 100 || e > 133) atomicAdd(&cnt, 1);
    __syncthreads();
    if (threadIdx.x == 0) *flag = (cnt >= 16) ? 1 : 0;   // 1 => float32 tensors
}

// ---------------- W transpose+convert: wt[m][j*64+c] = bf16(W_m[c*64+j]) ----------------
__global__ __launch_bounds__(256) void transpose_w_kernel(
    const void* __restrict__ W0, const void* __restrict__ W1,
    const void* __restrict__ W2, const void* __restrict__ W3,
    const void* __restrict__ W4, const void* __restrict__ W5,
    const int* __restrict__ flagp, unsigned short* __restrict__ wt)
{
    const int f32 = *flagp;
    const void* src;
    switch (blockIdx.x) {
        case 0: src = W0; break; case 1: src = W1; break; case 2: src = W2; break;
        case 3: src = W3; break; case 4: src = W4; break; default: src = W5; break;
    }
    unsigned short* dst = wt + blockIdx.x * 4096;
    for (int i = threadIdx.x; i < 4096; i += 256) {
        int c = i >> 6, j = i & 63;
        dst[j * 64 + c] = f2bf_bits(ldf(src, c * 64 + j, f32));
    }
}

// ---------------- node prep (MFMA): one 16-node tile per wave, x converted inline -------
__global__ __launch_bounds__(256) void node_prep_mfma_kernel(
    const void* __restrict__ x_a, const void* __restrict__ x_b,
    const unsigned short* __restrict__ wt,
    const void* __restrict__ emb_a, const void* __restrict__ emb_b,
    const void* __restrict__ a_attn, const int* __restrict__ flagp,
    float* __restrict__ v_a, float* __restrict__ v_b,
    float* __restrict__ sq_a, float* __restrict__ sk_a,
    float* __restrict__ sq_b, float* __restrict__ sk_b,
    int n_nodes, int tiles)
{
    const int f32 = *flagp;
    const int wave_id = blockIdx.x * 4 + (threadIdx.x >> 6);
    if (wave_id >= 2 * tiles) return;
    const int type = (wave_id >= tiles);
    const int tile = type ? (wave_id - tiles) : wave_id;

    const void* xp = type ? x_b : x_a;
    const unsigned short* wq = wt + (type ? 3 * 4096 : 0);
    const unsigned short* wk = wq + 4096;
    const unsigned short* wv = wk + 4096;
    const void* embp = type ? emb_b : emb_a;
    float*  v_out  = type ? v_b : v_a;
    float2* sq_out = (float2*)(type ? sq_b : sq_a);
    float2* sk_out = (float2*)(type ? sk_b : sk_a);

    const int lane = threadIdx.x & 63;
    const int ml   = lane & 15;        // node-row (A) / out-col (B,D)
    const int g    = lane >> 4;        // quad
    const int g8   = g * 8;

    float embc[4], acq[4], ack[4];
    #pragma unroll
    for (int t = 0; t < 4; ++t) {
        int colt = t * 16 + ml;
        embc[t] = ldf(embp, colt, f32);
        acq[t]  = ldf(a_attn, colt & 31, f32);
        ack[t]  = ldf(a_attn, 32 + (colt & 31), f32);
    }

    short8 Bq[4][2], Bk[4][2], Bv[4][2];
    #pragma unroll
    for (int t = 0; t < 4; ++t) {
        const int rowo = (t * 16 + ml) * 64;
        #pragma unroll
        for (int kh = 0; kh < 2; ++kh) {
            const int o = rowo + kh * 32 + g8;
            Bq[t][kh] = __builtin_bit_cast(short8, *(const uint4*)(wq + o));
            Bk[t][kh] = __builtin_bit_cast(short8, *(const uint4*)(wk + o));
            Bv[t][kh] = __builtin_bit_cast(short8, *(const uint4*)(wv + o));
        }
    }

    const int n0 = tile << 4;
    int nr = n0 + ml; if (nr > n_nodes - 1) nr = n_nodes - 1;
    short8 A0, A1;
    if (f32) {
        const float4* xr = (const float4*)((const float*)xp + (size_t)nr * 64);
        float4 f0 = xr[2*g], f1 = xr[2*g+1], f2 = xr[8+2*g], f3 = xr[9+2*g];
        short8 a0, a1;
        a0[0]=(short)f2bf_bits(f0.x); a0[1]=(short)f2bf_bits(f0.y);
        a0[2]=(short)f2bf_bits(f0.z); a0[3]=(short)f2bf_bits(f0.w);
        a0[4]=(short)f2bf_bits(f1.x); a0[5]=(short)f2bf_bits(f1.y);
        a0[6]=(short)f2bf_bits(f1.z); a0[7]=(short)f2bf_bits(f1.w);
        a1[0]=(short)f2bf_bits(f2.x); a1[1]=(short)f2bf_bits(f2.y);
        a1[2]=(short)f2bf_bits(f2.z); a1[3]=(short)f2bf_bits(f2.w);
        a1[4]=(short)f2bf_bits(f3.x); a1[5]=(short)f2bf_bits(f3.y);
        a1[6]=(short)f2bf_bits(f3.z); a1[7]=(short)f2bf_bits(f3.w);
        A0 = a0; A1 = a1;
    } else {
        const uint4* xr = (const uint4*)((const bf16*)xp + (size_t)nr * 64);
        A0 = __builtin_bit_cast(short8, xr[g]);
        A1 = __builtin_bit_cast(short8, xr[4 + g]);
    }

    float4v accq[4], acck[4], accv[4];
    #pragma unroll
    for (int t = 0; t < 4; ++t) {
        float4v z = {0.f, 0.f, 0.f, 0.f};
        accq[t] = z; acck[t] = z; accv[t] = z;
    }
    #pragma unroll
    for (int t = 0; t < 4; ++t) {
        accq[t] = __builtin_amdgcn_mfma_f32_16x16x32_bf16(A0, Bq[t][0], accq[t], 0, 0, 0);
        accq[t] = __builtin_amdgcn_mfma_f32_16x16x32_bf16(A1, Bq[t][1], accq[t], 0, 0, 0);
        acck[t] = __builtin_amdgcn_mfma_f32_16x16x32_bf16(A0, Bk[t][0], acck[t], 0, 0, 0);
        acck[t] = __builtin_amdgcn_mfma_f32_16x16x32_bf16(A1, Bk[t][1], acck[t], 0, 0, 0);
        accv[t] = __builtin_amdgcn_mfma_f32_16x16x32_bf16(A0, Bv[t][0], accv[t], 0, 0, 0);
        accv[t] = __builtin_amdgcn_mfma_f32_16x16x32_bf16(A1, Bv[t][1], accv[t], 0, 0, 0);
    }

    #pragma unroll
    for (int t = 0; t < 4; ++t) {
        #pragma unroll
        for (int r = 0; r < 4; ++r) {
            int node = n0 + g * 4 + r;
            if (node < n_nodes) v_out[(size_t)node * 64 + t * 16 + ml] = accv[t][r];
        }
    }

    #pragma unroll
    for (int r = 0; r < 4; ++r) {
        float q0 = fast_tanh(accq[0][r] + embc[0]) * acq[0]
                 + fast_tanh(accq[1][r] + embc[1]) * acq[1];
        float q1 = fast_tanh(accq[2][r] + embc[2]) * acq[2]
                 + fast_tanh(accq[3][r] + embc[3]) * acq[3];
        float k0 = fast_tanh(acck[0][r] + embc[0]) * ack[0]
                 + fast_tanh(acck[1][r] + embc[1]) * ack[1];
        float k1 = fast_tanh(acck[2][r] + embc[2]) * ack[2]
                 + fast_tanh(acck[3][r] + embc[3]) * ack[3];
        #pragma unroll
        for (int o = 1; o < 16; o <<= 1) {
            q0 += __shfl_xor(q0, o, 64); q1 += __shfl_xor(q1, o, 64);
            k0 += __shfl_xor(k0, o, 64); k1 += __shfl_xor(k1, o, 64);
        }
        int node = n0 + g * 4 + r;
        if (ml == 0 && node < n_nodes) {
            sq_out[node] = make_float2(q0, q1);
            sk_out[node] = make_float2(k0, k1);
        }
    }
}

// ---------------- relation constants: c[h] = sum_j tanh(rel[h,j]) * a[64+j'] ----------------
__global__ void rel_const_kernel(const void* __restrict__ rel1, const void* __restrict__ rel2,
                                 const void* __restrict__ a_attn, const int* __restrict__ flagp,
                                 float* __restrict__ cvals)
{
    const int f32 = *flagp;
    int t = threadIdx.x;             // 128 threads: wave0 -> rel1, wave1 -> rel2
    const void* r = (t < 64) ? rel1 : rel2;
    int l = t & 63;
    float v = tanhf(ldf(r, l, f32)) * ldf(a_attn, 64 + (l & 31), f32);
    #pragma unroll
    for (int off = 16; off; off >>= 1) v += __shfl_xor(v, off, 32);
    if ((l & 31) == 0) cvals[(t >> 6) * 2 + (l >> 5)] = v;
}

// ---------------- precompute (both relations): M = blockdiag(We@Wo), c32 = rel@Wo --------
__global__ void precompute_kernel(const void* __restrict__ We,
                                  const void* __restrict__ Wo_b, const void* __restrict__ Wo_a,
                                  const void* __restrict__ rel1, const void* __restrict__ rel2,
                                  const int* __restrict__ flagp,
                                  float* __restrict__ M1, float* __restrict__ c321,
                                  float* __restrict__ M2, float* __restrict__ c322)
{
    const int f32 = *flagp;
    const int sel = blockIdx.x;            // 0: rel1/Wo_b, 1: rel2/Wo_a
    const void* Wo = sel ? Wo_a : Wo_b;
    const void* rel = sel ? rel2 : rel1;
    float* M   = sel ? M2 : M1;
    float* c32 = sel ? c322 : c321;
    int t = threadIdx.x;            // 1024 threads
    int m = t >> 5, j = t & 31;
    int h = m >> 4, c = m & 15;
    float s = 0.f;
    for (int jj = 0; jj < 32; ++jj)
        s += ldf(We, c * 64 + h * 32 + jj, f32) * ldf(Wo, (size_t)(h * 32 + jj) * 32 + j, f32);
    M[m * 32 + j] = s;
    if (t < 32) {
        float s2 = 0.f;
        for (int ch = 0; ch < 64; ++ch)
            s2 += ldf(rel, ch, f32) * ldf(Wo, (size_t)ch * 32 + t, f32);
        c32[t] = s2;
    }
}

// ---------------- CSR build ----------------
__global__ __launch_bounds__(256) void hist_kernel(
    const int* __restrict__ col1, const int* __restrict__ col2,
    int* __restrict__ cnt, int nb, int n_nodes, int num_e)
{
    const int sel = (blockIdx.x >= nb) ? 1 : 0;
    const int bx  = sel ? blockIdx.x - nb : blockIdx.x;
    const int* col = sel ? col2 : col1;
    const int rb = sel ? n_nodes : 0;
    int e = bx * 256 + threadIdx.x;
    if (e < num_e) atomicAdd(&cnt[rb + col[e]], 1);
}

__global__ __launch_bounds__(256) void scan1_kernel(const int* __restrict__ cnt,
                                                    int* __restrict__ partial, int n)
{
    __shared__ int wsum[4];
    int t = threadIdx.x;
    int i0 = blockIdx.x * 512 + 2 * t;
    int s = ((i0 < n) ? cnt[i0] : 0) + ((i0 + 1 < n) ? cnt[i0 + 1] : 0);
    #pragma unroll
    for (int o = 32; o; o >>= 1) s += __shfl_xor(s, o, 64);
    if ((t & 63) == 0) wsum[t >> 6] = s;
    __syncthreads();
    if (t == 0) partial[blockIdx.x] = wsum[0] + wsum[1] + wsum[2] + wsum[3];
}

__global__ void scan2_kernel(const int* __restrict__ partial, int* __restrict__ pp,
                             int* __restrict__ off, int nch, int noff)
{
    int lane = threadIdx.x;   // 64 threads
    int running = 0;
    for (int base = 0; base < nch; base += 64) {
        int i = base + lane;
        int o = (i < nch) ? partial[i] : 0;
        int v = o;
        #pragma unroll
        for (int d = 1; d < 64; d <<= 1) {
            int u = __shfl_up(v, d, 64);
            if (lane >= d) v += u;
        }
        if (i < nch) pp[i] = running + v - o;
        running += __shfl(v, 63, 64);
    }
    if (lane == 0) off[noff] = running;
}

__global__ __launch_bounds__(256) void scan3_kernel(const int* __restrict__ cnt,
                                                    const int* __restrict__ pp,
                                                    int* __restrict__ off,
                                                    int* __restrict__ cursor, int n)
{
    __shared__ int tmp[256];
    int t = threadIdx.x;
    int i0 = blockIdx.x * 512 + 2 * t;
    int v0 = (i0 < n) ? cnt[i0] : 0;
    int v1 = (i0 + 1 < n) ? cnt[i0 + 1] : 0;
    int pair = v0 + v1;
    tmp[t] = pair;
    __syncthreads();
    for (int d = 1; d < 256; d <<= 1) {
        int x = (t >= d) ? tmp[t - d] : 0;
        __syncthreads();
        tmp[t] += x;
        __syncthreads();
    }
    int excl = tmp[t] - pair + pp[blockIdx.x];
    if (i0 < n)     { off[i0] = excl;          cursor[i0] = excl; }
    if (i0 + 1 < n) { off[i0 + 1] = excl + v0; cursor[i0 + 1] = excl + v0; }
}

// ---------------- fused edge scores + scatter (both relations, one launch) ----------------
// Writes a 48B CSR record per edge: {src, ex0, ex1, pad, ea[16] bf16} so the
// aggregation pass reads everything sequentially (no random ea gather).
__global__ __launch_bounds__(256) void edge_score_scatter_kernel(
    const void* __restrict__ ea1p, const void* __restrict__ ea2p,
    const void* __restrict__ We,
    const int* __restrict__ row1, const int* __restrict__ col1,
    const int* __restrict__ row2, const int* __restrict__ col2,
    const float* __restrict__ sq_bp, const float* __restrict__ sk_ap,
    const float* __restrict__ sq_ap, const float* __restrict__ sk_bp,
    const float* __restrict__ cvals, const void* __restrict__ a_attn,
    const int* __restrict__ flagp, int* __restrict__ cursor,
    uint4* __restrict__ payload, int nb, int n_nodes, int num_e)
{
    const int f32 = *flagp;
    const int sel = (blockIdx.x >= nb) ? 1 : 0;
    const int bx  = sel ? blockIdx.x - nb : blockIdx.x;
    const void* ea = sel ? ea2p : ea1p;
    const int* row = sel ? row2 : row1;
    const int* col = sel ? col2 : col1;
    const float* sq_dst = sel ? sq_ap : sq_bp;
    const float* sk_src = sel ? sk_bp : sk_ap;
    const int rb = sel ? n_nodes : 0;

    __shared__ float We_s[16 * 64];
    __shared__ float a3_s[32];
    for (int i = threadIdx.x; i < 16 * 64; i += 256) We_s[i] = ldf(We, i, f32);
    if (threadIdx.x < 32) a3_s[threadIdx.x] = ldf(a_attn, 96 + threadIdx.x, f32);
    const float c0 = cvals[sel * 2 + 0];
    const float c1 = cvals[sel * 2 + 1];
    __syncthreads();

    const int e0 = bx * 512 + threadIdx.x;
    const int e1 = e0 + 256;
    const bool v1e = (e1 < num_e);
    if (e0 >= num_e) return;

    float er0[16], er1[16];
    load_ea16(ea, (size_t)e0, f32, er0);
    if (v1e) load_ea16(ea, (size_t)e1, f32, er1);
    else {
        #pragma unroll
        for (int c = 0; c < 16; ++c) er1[c] = 0.f;
    }

    float acc00 = 0.f, acc01 = 0.f, acc10 = 0.f, acc11 = 0.f;
    #pragma unroll 1                       // keep rolled: avoids VGPR blowup/spills
    for (int jb = 0; jb < 64; jb += 16) {
        float t0[16], t1[16];
        #pragma unroll
        for (int jj = 0; jj < 16; ++jj) { t0[jj] = 0.f; t1[jj] = 0.f; }
        #pragma unroll
        for (int c = 0; c < 16; ++c) {
            #pragma unroll
            for (int jj = 0; jj < 16; ++jj) {
                float w = We_s[c * 64 + jb + jj];   // uniform broadcast
                t0[jj] += er0[c] * w;
                t1[jj] += er1[c] * w;
            }
        }
        float p0 = 0.f, p1 = 0.f;
        #pragma unroll
        for (int jj = 0; jj < 16; ++jj) {
            float a = a3_s[(jb + jj) & 31];
            p0 += fast_tanh(t0[jj]) * a;
            p1 += fast_tanh(t1[jj]) * a;
        }
        if (jb & 32) { acc01 += p0; acc11 += p1; }
        else         { acc00 += p0; acc10 += p1; }
    }

    {
        int dc = col[e0], s = row[e0];
        float2 sqd = ((const float2*)sq_dst)[dc];
        float2 sks = ((const float2*)sk_src)[s];
        float s0 = fminf(30.f, fmaxf(-30.f, acc00 + sqd.x + sks.x + c0));
        float s1 = fminf(30.f, fmaxf(-30.f, acc01 + sqd.y + sks.y + c1));
        int pos = atomicAdd(&cursor[rb + dc], 1);
        uint4* rec = payload + (size_t)3 * pos;
        unsigned w0 = (unsigned)f2bf_bits(er0[0])  | ((unsigned)f2bf_bits(er0[1])  << 16);
        unsigned w1 = (unsigned)f2bf_bits(er0[2])  | ((unsigned)f2bf_bits(er0[3])  << 16);
        unsigned w2 = (unsigned)f2bf_bits(er0[4])  | ((unsigned)f2bf_bits(er0[5])  << 16);
        unsigned w3 = (unsigned)f2bf_bits(er0[6])  | ((unsigned)f2bf_bits(er0[7])  << 16);
        unsigned w4 = (unsigned)f2bf_bits(er0[8])  | ((unsigned)f2bf_bits(er0[9])  << 16);
        unsigned w5 = (unsigned)f2bf_bits(er0[10]) | ((unsigned)f2bf_bits(er0[11]) << 16);
        unsigned w6 = (unsigned)f2bf_bits(er0[12]) | ((unsigned)f2bf_bits(er0[13]) << 16);
        unsigned w7 = (unsigned)f2bf_bits(er0[14]) | ((unsigned)f2bf_bits(er0[15]) << 16);
        rec[0] = make_uint4((unsigned)s, __float_as_uint(__expf(s0)), __float_as_uint(__expf(s1)), 0u);
        rec[1] = make_uint4(w0, w1, w2, w3);
        rec[2] = make_uint4(w4, w5, w6, w7);
    }
    if (v1e) {
        int dc = col[e1], s = row[e1];
        float2 sqd = ((const float2*)sq_dst)[dc];
        float2 sks = ((const float2*)sk_src)[s];
        float s0 = fminf(30.f, fmaxf(-30.f, acc10 + sqd.x + sks.x + c0));
        float s1 = fminf(30.f, fmaxf(-30.f, acc11 + sqd.y + sks.y + c1));
        int pos = atomicAdd(&cursor[rb + dc], 1);
        uint4* rec = payload + (size_t)3 * pos;
        unsigned w0 = (unsigned)f2bf_bits(er1[0])  | ((unsigned)f2bf_bits(er1[1])  << 16);
        unsigned w1 = (unsigned)f2bf_bits(er1[2])  | ((unsigned)f2bf_bits(er1[3])  << 16);
        unsigned w2 = (unsigned)f2bf_bits(er1[4])  | ((unsigned)f2bf_bits(er1[5])  << 16);
        unsigned w3 = (unsigned)f2bf_bits(er1[6])  | ((unsigned)f2bf_bits(er1[7])  << 16);
        unsigned w4 = (unsigned)f2bf_bits(er1[8])  | ((unsigned)f2bf_bits(er1[9])  << 16);
        unsigned w5 = (unsigned)f2bf_bits(er1[10]) | ((unsigned)f2bf_bits(er1[11]) << 16);
        unsigned w6 = (unsigned)f2bf_bits(er1[12]) | ((unsigned)f2bf_bits(er1[13]) << 16);
        unsigned w7 = (unsigned)f2bf_bits(er1[14]) | ((unsigned)f2bf_bits(er1[15]) << 16);
        rec[0] = make_uint4((unsigned)s, __float_as_uint(__expf(s0)), __float_as_uint(__expf(s1)), 0u);
        rec[1] = make_uint4(w0, w1, w2, w3);
        rec[2] = make_uint4(w4, w5, w6, w7);
    }
}

// ---------------- fused aggregation + output projection (both relations, one launch) -----
// Single pass per node (normalize at the end), sequential 48B records, unroll-4
// batched loads for MLP, and wave-private LDS staging (no block barrier).
__global__ __launch_bounds__(256) void agg_final_kernel(
    const uint4* __restrict__ payload, const int* __restrict__ off,
    const float* __restrict__ v_a, const float* __restrict__ v_b,
    const void* __restrict__ x_a, const void* __restrict__ x_b,
    const void* __restrict__ Wo_a, const void* __restrict__ Wo_b,
    const void* __restrict__ bo_a, const void* __restrict__ bo_b,
    const void* __restrict__ Wr_a, const void* __restrict__ Wr_b,
    const float* __restrict__ M1, const float* __restrict__ M2,
    const float* __restrict__ c321, const float* __restrict__ c322,
    const int* __restrict__ flagp, void* __restrict__ out,
    int n_nodes, int nbh)
{
    const int sel = (blockIdx.x >= nbh) ? 1 : 0;   // 0: rel1 (dst=b), 1: rel2 (dst=a)
    const int bx  = sel ? blockIdx.x - nbh : blockIdx.x;
    const float* v_src = sel ? v_b : v_a;
    const void*  x     = sel ? x_a : x_b;
    const void*  Wo    = sel ? Wo_a : Wo_b;
    const void*  bo    = sel ? bo_a : bo_b;
    const void*  Wr    = sel ? Wr_a : Wr_b;
    const float* M     = sel ? M2 : M1;
    const float* c32   = sel ? c322 : c321;
    const int relbase  = sel ? n_nodes : 0;
    const size_t out_off = sel ? 0 : (size_t)n_nodes * 32;

    const int f32  = *flagp;
    const int lane = threadIdx.x & 63;
    const int wv   = threadIdx.x >> 6;
    const int j    = lane & 31;
    const int half = lane >> 5;
    const int c16  = lane & 15;
    const bool hi  = (lane >= 32);

    __shared__ float stage[4][160];   // per-wave: y[64] | x[64] | u[32]

    float WoR[32], WrR[32], MR[16];
    const int cb = half * 32;
    #pragma unroll
    for (int cc = 0; cc < 32; ++cc) {
        WoR[cc] = ldf(Wo, (size_t)(cb + cc) * 32 + j, f32);
        WrR[cc] = ldf(Wr, (size_t)(cb + cc) * 32 + j, f32);
    }
    const int ub = half * 16;
    #pragma unroll
    for (int cc = 0; cc < 16; ++cc) MR[cc] = M[(ub + cc) * 32 + j];
    const float boR  = ldf(bo, j, f32);
    const float c32R = c32[j];

    const int stride = nbh * 4;
    const int iters  = (n_nodes + stride - 1) / stride;
    int d = bx * 4 + wv;

    for (int it = 0; it < iters; ++it, d += stride) {
        const bool valid = (d < n_nodes);
        const int dd  = valid ? d : (n_nodes - 1);
        const int idx = relbase + dd;
        const int b   = __builtin_amdgcn_readfirstlane(off[idx]);
        const int en  = __builtin_amdgcn_readfirstlane(off[idx + 1]);
        const int deg = en - b;

        float den0 = 0.f, den1 = 0.f, y = 0.f, ua = 0.f;
        int k = b;
        #pragma unroll 1
        for (; k + 4 <= en; k += 4) {
            uint4 m0 = payload[(size_t)3 * (k + 0)];
            uint4 m1 = payload[(size_t)3 * (k + 1)];
            uint4 m2 = payload[(size_t)3 * (k + 2)];
            uint4 m3 = payload[(size_t)3 * (k + 3)];
            const unsigned short* p0 = (const unsigned short*)(payload + (size_t)3 * (k + 0) + 1);
            const unsigned short* p1 = (const unsigned short*)(payload + (size_t)3 * (k + 1) + 1);
            const unsigned short* p2 = (const unsigned short*)(payload + (size_t)3 * (k + 2) + 1);
            const unsigned short* p3 = (const unsigned short*)(payload + (size_t)3 * (k + 3) + 1);
            float vv0 = v_src[(size_t)m0.x * 64 + lane];
            float vv1 = v_src[(size_t)m1.x * 64 + lane];
            float vv2 = v_src[(size_t)m2.x * 64 + lane];
            float vv3 = v_src[(size_t)m3.x * 64 + lane];
            float ea0 = __uint_as_float((unsigned)p0[c16] << 16);
            float ea1 = __uint_as_float((unsigned)p1[c16] << 16);
            float ea2 = __uint_as_float((unsigned)p2[c16] << 16);
            float ea3 = __uint_as_float((unsigned)p3[c16] << 16);
            float e00 = __uint_as_float(m0.y), e01 = __uint_as_float(m0.z);
            float e10 = __uint_as_float(m1.y), e11 = __uint_as_float(m1.z);
            float e20 = __uint_as_float(m2.y), e21 = __uint_as_float(m2.z);
            float e30 = __uint_as_float(m3.y), e31 = __uint_as_float(m3.z);
            den0 += e00 + e10 + e20 + e30;
            den1 += e01 + e11 + e21 + e31;
            float x0 = hi ? e01 : e00;
            float x1 = hi ? e11 : e10;
            float x2 = hi ? e21 : e20;
            float x3 = hi ? e31 : e30;
            y  = fmaf(x0, vv0, y);  y  = fmaf(x1, vv1, y);
            y  = fmaf(x2, vv2, y);  y  = fmaf(x3, vv3, y);
            ua = fmaf(x0, ea0, ua); ua = fmaf(x1, ea1, ua);
            ua = fmaf(x2, ea2, ua); ua = fmaf(x3, ea3, ua);
        }
        for (; k < en; ++k) {
            uint4 m0 = payload[(size_t)3 * k];
            const unsigned short* p0 = (const unsigned short*)(payload + (size_t)3 * k + 1);
            float vv0 = v_src[(size_t)m0.x * 64 + lane];
            float ea0 = __uint_as_float((unsigned)p0[c16] << 16);
            float e00 = __uint_as_float(m0.y), e01 = __uint_as_float(m0.z);
            den0 += e00; den1 += e01;
            float x0 = hi ? e01 : e00;
            y  = fmaf(x0, vv0, y);
            ua = fmaf(x0, ea0, ua);
        }

        float inv0 = (deg > 0) ? __builtin_amdgcn_rcpf(den0) : 0.f;
        float inv1 = (deg > 0) ? __builtin_amdgcn_rcpf(den1) : 0.f;
        const float invh = hi ? inv1 : inv0;
        y  *= invh;
        ua *= invh;

        float xv = ldf(x, (size_t)dd * 64 + lane, f32);

        // wave-private LDS staging: no block barrier needed (lockstep wave64 +
        // lgkmcnt drain orders the cross-lane LDS traffic within the wave).
        float* st = stage[wv];
        st[lane] = y;
        st[64 + lane] = xv;
        if ((lane & 31) < 16) st[128 + half * 16 + c16] = ua;
        __asm__ volatile("s_waitcnt lgkmcnt(0)" ::: "memory");

        float acc = 0.f;
        #pragma unroll
        for (int cc = 0; cc < 32; ++cc) {
            acc = fmaf(st[cb + cc], WoR[cc], acc);
            acc = fmaf(st[64 + cb + cc], WrR[cc], acc);
        }
        #pragma unroll
        for (int cc = 0; cc < 16; ++cc)
            acc = fmaf(st[128 + ub + cc], MR[cc], acc);

        float other = __shfl(acc, lane ^ 32, 64);
        if (valid && lane < 32) {
            float o = acc + other + boR + ((deg > 0) ? c32R : 0.f);
            stf(out, out_off + (size_t)dd * 32 + j, f32, o);
        }
        __asm__ volatile("" ::: "memory");
        __builtin_amdgcn_wave_barrier();
    }
}

extern "C" void kernel_launch(void* const* d_in, const int* in_sizes, int n_in,
                              void* d_out, int out_size, void* d_ws, size_t ws_size,
                              hipStream_t stream)
{
    const void* x_a   = d_in[0];
    const void* x_b   = d_in[1];
    const void* ea1   = d_in[2];
    const void* ea2   = d_in[3];
    const void* Wq_a  = d_in[4];
    const void* Wk_a  = d_in[5];
    const void* Wv_a  = d_in[6];
    const void* Wq_b  = d_in[7];
    const void* Wk_b  = d_in[8];
    const void* Wv_b  = d_in[9];
    const void* emb_a = d_in[10];
    const void* emb_b = d_in[11];
    const void* rel1  = d_in[12];
    const void* rel2  = d_in[13];
    const void* We    = d_in[14];
    const void* a_at  = d_in[15];
    const void* Wo_a  = d_in[16];
    const void* bo_a  = d_in[17];
    const void* Wo_b  = d_in[18];
    const void* bo_b  = d_in[19];
    const void* Wr_a  = d_in[20];
    const void* Wr_b  = d_in[21];
    const int*  row1  = (const int*)d_in[22];
    const int*  col1  = (const int*)d_in[23];
    const int*  row2  = (const int*)d_in[24];
    const int*  col2  = (const int*)d_in[25];

    const int N = in_sizes[0] / 64;   // nodes per type
    const int E = in_sizes[22];       // edges per relation

    // ---- workspace layout ----
    float* ws = (float*)d_ws;
    size_t off = 0;
    int*   flag = (int*)ws;        off += 64;
    float* v_a  = ws + off;        off += (size_t)N * 64;
    float* v_b  = ws + off;        off += (size_t)N * 64;
    float* sq_a = ws + off;        off += (size_t)N * 2;
    float* sk_a = ws + off;        off += (size_t)N * 2;
    float* sq_b = ws + off;        off += (size_t)N * 2;
    float* sk_b = ws + off;        off += (size_t)N * 2;
    float* cvals = ws + off;       off += 4;
    off = (off + 3) & ~(size_t)3;  // 16B align
    unsigned short* wt = (unsigned short*)(ws + off); off += 6 * 4096 / 2;  // 6 transposed 64x64 bf16
    float* M1   = ws + off;        off += 1024;
    float* c321 = ws + off;        off += 32;
    float* M2   = ws + off;        off += 1024;
    float* c322 = ws + off;        off += 32;
    int*   cnt    = (int*)(ws + off);  off += (size_t)2 * N;
    int*   offs   = (int*)(ws + off);  off += (size_t)2 * N + 2;
    int*   cursor = (int*)(ws + off);  off += (size_t)2 * N;
    int*   partial = (int*)(ws + off); off += 512;
    int*   pp      = (int*)(ws + off); off += 512;
    off = (off + 3) & ~(size_t)3;     // 16B align for uint4
    uint4* payload = (uint4*)(ws + off); off += (size_t)2 * E * 12;  // 48B records

    const int tiles        = (N + 15) >> 4;
    const int mfma_blocks  = (2 * tiles + 3) / 4;       // one tile per wave, both types
    const int score_blocks = (E + 511) / 512;
    const int eb_blocks    = (E + 255) / 256;
    const int nch          = (2 * N + 511) / 512;
    const int agg_half     = 2048;                      // blocks per relation

    detect_kernel<<<1, 128, 0, stream>>>((const unsigned short*)a_at, flag);
    hipMemsetAsync(cnt, 0, (size_t)2 * N * sizeof(int), stream);

    transpose_w_kernel<<<6, 256, 0, stream>>>(Wq_a, Wk_a, Wv_a, Wq_b, Wk_b, Wv_b, flag, wt);
    node_prep_mfma_kernel<<<mfma_blocks, 256, 0, stream>>>(
        x_a, x_b, wt, emb_a, emb_b, a_at, flag,
        v_a, v_b, sq_a, sk_a, sq_b, sk_b, N, tiles);

    rel_const_kernel<<<1, 128, 0, stream>>>(rel1, rel2, a_at, flag, cvals);
    precompute_kernel<<<2, 1024, 0, stream>>>(We, Wo_b, Wo_a, rel1, rel2, flag,
                                              M1, c321, M2, c322);

    hist_kernel<<<2 * eb_blocks, 256, 0, stream>>>(col1, col2, cnt, eb_blocks, N, E);
    scan1_kernel<<<nch, 256, 0, stream>>>(cnt, partial, 2 * N);
    scan2_kernel<<<1, 64, 0, stream>>>(partial, pp, offs, nch, 2 * N);
    scan3_kernel<<<nch, 256, 0, stream>>>(cnt, pp, offs, cursor, 2 * N);

    edge_score_scatter_kernel<<<2 * score_blocks, 256, 0, stream>>>(
        ea1, ea2, We, row1, col1, row2, col2,
        sq_b, sk_a, sq_a, sk_b, cvals, a_at, flag,
        cursor, payload, score_blocks, N, E);

    agg_final_kernel<<<2 * agg_half, 256, 0, stream>>>(
        payload, offs, v_a, v_b, x_a, x_b, Wo_a, Wo_b, bo_a, bo_b, Wr_a, Wr_b,
        M1, M2, c321, c322, flag, d_out, N, agg_half);
}

// Round 2
// 527.333 us; speedup vs baseline: 1.3686x; 1.1017x over previous
//
#include <hip/hip_runtime.h>
#include <hip/hip_bf16.h>

typedef __hip_bfloat16 bf16;
typedef __attribute__((ext_vector_type(8))) short short8;
typedef __attribute__((ext_vector_type(4))) float float4v;

static __device__ __forceinline__ float b2f(bf16 x) { return __bfloat162float(x); }

// dtype-dispatched load/store: f32=1 -> buffer is float32, f32=0 -> bfloat16.
static __device__ __forceinline__ float ldf(const void* p, size_t i, int f32) {
    return f32 ? ((const float*)p)[i] : b2f(((const bf16*)p)[i]);
}
static __device__ __forceinline__ void stf(void* p, size_t i, int f32, float v) {
    if (f32) ((float*)p)[i] = v;
    else     ((bf16*)p)[i] = __float2bfloat16(v);
}
static __device__ __forceinline__ unsigned short f2bf_bits(float f) {
    bf16 h = __float2bfloat16(f);
    return *(unsigned short*)&h;
}

// fast tanh: 1 - 2/(e^2x + 1)
static __device__ __forceinline__ float fast_tanh(float x) {
    float t = __expf(2.f * x);
    return 1.f - 2.f * __builtin_amdgcn_rcpf(t + 1.f);
}

// load 16 edge-attr channels of edge e into registers (either dtype)
static __device__ __forceinline__ void load_ea16(const void* ea, size_t e, int f32, float* er) {
    if (f32) {
        const float4* p = (const float4*)((const float*)ea + e * 16);
        #pragma unroll
        for (int q = 0; q < 4; ++q) {
            float4 v = p[q];
            er[4*q] = v.x; er[4*q+1] = v.y; er[4*q+2] = v.z; er[4*q+3] = v.w;
        }
    } else {
        const uint4* p = (const uint4*)((const bf16*)ea + e * 16);
        #pragma unroll
        for (int q = 0; q < 2; ++q) {
            uint4 u = p[q];
            er[8*q+0] = __uint_as_float(u.x << 16);
            er[8*q+1] = __uint_as_float(u.x & 0xffff0000u);
            er[8*q+2] = __uint_as_float(u.y << 16);
            er[8*q+3] = __uint_as_float(u.y & 0xffff0000u);
            er[8*q+4] = __uint_as_float(u.z << 16);
            er[8*q+5] = __uint_as_float(u.z & 0xffff0000u);
            er[8*q+6] = __uint_as_float(u.w << 16);
            er[8*q+7] = __uint_as_float(u.w & 0xffff0000u);
        }
    }
}

// ---------------- dtype detector ----------------
__global__ void detect_kernel(const unsigned short* __restrict__ a, int* __restrict__ flag)
{
    __shared__ int cnt;
    if (threadIdx.x == 0) cnt = 0;
    __syncthreads();
    unsigned e = (a[threadIdx.x] >> 7) & 0xFF;
    if (e < 100 || e > 133) atomicAdd(&cnt, 1);
    __syncthreads();
    if (threadIdx.x == 0) *flag = (cnt >= 16) ? 1 : 0;   // 1 => float32 tensors
}

// ---------------- small prep: W transposes + M/c32/cvals precompute (one launch) --------
// blocks 0..5: 64x64 W transpose; 6..7: 64x32 Wr transpose; 8..9: precompute per relation
__global__ __launch_bounds__(256) void prep_small_kernel(
    const void* __restrict__ W0, const void* __restrict__ W1,
    const void* __restrict__ W2, const void* __restrict__ W3,
    const void* __restrict__ W4, const void* __restrict__ W5,
    const void* __restrict__ Wr_a, const void* __restrict__ Wr_b,
    const void* __restrict__ We,
    const void* __restrict__ Wo_a, const void* __restrict__ Wo_b,
    const void* __restrict__ rel1, const void* __restrict__ rel2,
    const void* __restrict__ a_attn, const int* __restrict__ flagp,
    unsigned short* __restrict__ wt,
    float* __restrict__ M1, float* __restrict__ c321,
    float* __restrict__ M2, float* __restrict__ c322,
    float* __restrict__ cvals)
{
    const int f32 = *flagp;
    const int bid = blockIdx.x;
    if (bid < 6) {
        const void* src;
        switch (bid) {
            case 0: src = W0; break; case 1: src = W1; break; case 2: src = W2; break;
            case 3: src = W3; break; case 4: src = W4; break; default: src = W5; break;
        }
        unsigned short* dst = wt + bid * 4096;
        for (int i = threadIdx.x; i < 4096; i += 256) {
            int c = i >> 6, j = i & 63;
            dst[j * 64 + c] = f2bf_bits(ldf(src, c * 64 + j, f32));
        }
    } else if (bid < 8) {
        const void* src = (bid == 6) ? Wr_a : Wr_b;
        unsigned short* dst = wt + 24576 + (bid - 6) * 2048;
        for (int i = threadIdx.x; i < 2048; i += 256) {
            int c = i >> 5, j = i & 31;          // c: 64 in-rows, j: 32 out-cols
            dst[j * 64 + c] = f2bf_bits(ldf(src, c * 32 + j, f32));
        }
    } else {
        const int sel = bid - 8;                 // 0: rel1/Wo_b, 1: rel2/Wo_a
        const void* Wo  = sel ? Wo_a : Wo_b;
        const void* rel = sel ? rel2 : rel1;
        float* M   = sel ? M2 : M1;
        float* c32 = sel ? c322 : c321;
        const int t = threadIdx.x;
        for (int i = t; i < 1024; i += 256) {
            int m = i >> 5, j = i & 31;
            int h = m >> 4, c = m & 15;
            float s = 0.f;
            for (int jj = 0; jj < 32; ++jj)
                s += ldf(We, c * 64 + h * 32 + jj, f32) * ldf(Wo, (size_t)(h * 32 + jj) * 32 + j, f32);
            M[m * 32 + j] = s;
        }
        if (t < 32) {
            float s2 = 0.f;
            for (int ch = 0; ch < 64; ++ch)
                s2 += ldf(rel, ch, f32) * ldf(Wo, (size_t)ch * 32 + t, f32);
            c32[t] = s2;
        }
        if (t == 252 || t == 253) {
            int h = t - 252;
            float s3 = 0.f;
            for (int l = 0; l < 32; ++l)
                s3 += tanhf(ldf(rel, h * 32 + l, f32)) * ldf(a_attn, 64 + l, f32);
            cvals[sel * 2 + h] = s3;
        }
    }
}

// ---------------- node prep (MFMA): q/k scores, v (bf16), r = x@Wr ----------------
__global__ __launch_bounds__(256) void node_prep_mfma_kernel(
    const void* __restrict__ x_a, const void* __restrict__ x_b,
    const unsigned short* __restrict__ wt,
    const void* __restrict__ emb_a, const void* __restrict__ emb_b,
    const void* __restrict__ a_attn, const int* __restrict__ flagp,
    unsigned short* __restrict__ v_a, unsigned short* __restrict__ v_b,
    float* __restrict__ r_a, float* __restrict__ r_b,
    float* __restrict__ sq_a, float* __restrict__ sk_a,
    float* __restrict__ sq_b, float* __restrict__ sk_b,
    int n_nodes, int tiles)
{
    const int f32 = *flagp;
    const int wave_id = blockIdx.x * 4 + (threadIdx.x >> 6);
    if (wave_id >= 2 * tiles) return;
    const int type = (wave_id >= tiles);
    const int tile = type ? (wave_id - tiles) : wave_id;

    const void* xp = type ? x_b : x_a;
    const unsigned short* wq = wt + (type ? 3 * 4096 : 0);
    const unsigned short* wk = wq + 4096;
    const unsigned short* wv = wk + 4096;
    const unsigned short* wr = wt + 24576 + (type ? 2048 : 0);
    const void* embp = type ? emb_b : emb_a;
    unsigned short* v_out = type ? v_b : v_a;
    float*  r_out  = type ? r_b : r_a;
    float2* sq_out = (float2*)(type ? sq_b : sq_a);
    float2* sk_out = (float2*)(type ? sk_b : sk_a);

    const int lane = threadIdx.x & 63;
    const int ml   = lane & 15;        // node-row (A) / out-col (B,D)
    const int g    = lane >> 4;        // quad
    const int g8   = g * 8;

    float embc[4], acq[4], ack[4];
    #pragma unroll
    for (int t = 0; t < 4; ++t) {
        int colt = t * 16 + ml;
        embc[t] = ldf(embp, colt, f32);
        acq[t]  = ldf(a_attn, colt & 31, f32);
        ack[t]  = ldf(a_attn, 32 + (colt & 31), f32);
    }

    short8 Bq[4][2], Bk[4][2], Bv[4][2], Br[2][2];
    #pragma unroll
    for (int t = 0; t < 4; ++t) {
        const int rowo = (t * 16 + ml) * 64;
        #pragma unroll
        for (int kh = 0; kh < 2; ++kh) {
            const int o = rowo + kh * 32 + g8;
            Bq[t][kh] = __builtin_bit_cast(short8, *(const uint4*)(wq + o));
            Bk[t][kh] = __builtin_bit_cast(short8, *(const uint4*)(wk + o));
            Bv[t][kh] = __builtin_bit_cast(short8, *(const uint4*)(wv + o));
            if (t < 2)
                Br[t][kh] = __builtin_bit_cast(short8, *(const uint4*)(wr + o));
        }
    }

    const int n0 = tile << 4;
    int nr = n0 + ml; if (nr > n_nodes - 1) nr = n_nodes - 1;
    short8 A0, A1;
    if (f32) {
        const float4* xr = (const float4*)((const float*)xp + (size_t)nr * 64);
        float4 f0 = xr[2*g], f1 = xr[2*g+1], f2 = xr[8+2*g], f3 = xr[9+2*g];
        short8 a0, a1;
        a0[0]=(short)f2bf_bits(f0.x); a0[1]=(short)f2bf_bits(f0.y);
        a0[2]=(short)f2bf_bits(f0.z); a0[3]=(short)f2bf_bits(f0.w);
        a0[4]=(short)f2bf_bits(f1.x); a0[5]=(short)f2bf_bits(f1.y);
        a0[6]=(short)f2bf_bits(f1.z); a0[7]=(short)f2bf_bits(f1.w);
        a1[0]=(short)f2bf_bits(f2.x); a1[1]=(short)f2bf_bits(f2.y);
        a1[2]=(short)f2bf_bits(f2.z); a1[3]=(short)f2bf_bits(f2.w);
        a1[4]=(short)f2bf_bits(f3.x); a1[5]=(short)f2bf_bits(f3.y);
        a1[6]=(short)f2bf_bits(f3.z); a1[7]=(short)f2bf_bits(f3.w);
        A0 = a0; A1 = a1;
    } else {
        const uint4* xr = (const uint4*)((const bf16*)xp + (size_t)nr * 64);
        A0 = __builtin_bit_cast(short8, xr[g]);
        A1 = __builtin_bit_cast(short8, xr[4 + g]);
    }

    float4v accq[4], acck[4], accv[4], accr[2];
    #pragma unroll
    for (int t = 0; t < 4; ++t) {
        float4v z = {0.f, 0.f, 0.f, 0.f};
        accq[t] = z; acck[t] = z; accv[t] = z;
        if (t < 2) accr[t] = z;
    }
    #pragma unroll
    for (int t = 0; t < 4; ++t) {
        accq[t] = __builtin_amdgcn_mfma_f32_16x16x32_bf16(A0, Bq[t][0], accq[t], 0, 0, 0);
        accq[t] = __builtin_amdgcn_mfma_f32_16x16x32_bf16(A1, Bq[t][1], accq[t], 0, 0, 0);
        acck[t] = __builtin_amdgcn_mfma_f32_16x16x32_bf16(A0, Bk[t][0], acck[t], 0, 0, 0);
        acck[t] = __builtin_amdgcn_mfma_f32_16x16x32_bf16(A1, Bk[t][1], acck[t], 0, 0, 0);
        accv[t] = __builtin_amdgcn_mfma_f32_16x16x32_bf16(A0, Bv[t][0], accv[t], 0, 0, 0);
        accv[t] = __builtin_amdgcn_mfma_f32_16x16x32_bf16(A1, Bv[t][1], accv[t], 0, 0, 0);
        if (t < 2) {
            accr[t] = __builtin_amdgcn_mfma_f32_16x16x32_bf16(A0, Br[t][0], accr[t], 0, 0, 0);
            accr[t] = __builtin_amdgcn_mfma_f32_16x16x32_bf16(A1, Br[t][1], accr[t], 0, 0, 0);
        }
    }

    #pragma unroll
    for (int t = 0; t < 4; ++t) {
        #pragma unroll
        for (int r = 0; r < 4; ++r) {
            int node = n0 + g * 4 + r;
            if (node < n_nodes) {
                v_out[(size_t)node * 64 + t * 16 + ml] = f2bf_bits(accv[t][r]);
                if (t < 2) r_out[(size_t)node * 32 + t * 16 + ml] = accr[t][r];
            }
        }
    }

    #pragma unroll
    for (int r = 0; r < 4; ++r) {
        float q0 = fast_tanh(accq[0][r] + embc[0]) * acq[0]
                 + fast_tanh(accq[1][r] + embc[1]) * acq[1];
        float q1 = fast_tanh(accq[2][r] + embc[2]) * acq[2]
                 + fast_tanh(accq[3][r] + embc[3]) * acq[3];
        float k0 = fast_tanh(acck[0][r] + embc[0]) * ack[0]
                 + fast_tanh(acck[1][r] + embc[1]) * ack[1];
        float k1 = fast_tanh(acck[2][r] + embc[2]) * ack[2]
                 + fast_tanh(acck[3][r] + embc[3]) * ack[3];
        #pragma unroll
        for (int o = 1; o < 16; o <<= 1) {
            q0 += __shfl_xor(q0, o, 64); q1 += __shfl_xor(q1, o, 64);
            k0 += __shfl_xor(k0, o, 64); k1 += __shfl_xor(k1, o, 64);
        }
        int node = n0 + g * 4 + r;
        if (ml == 0 && node < n_nodes) {
            sq_out[node] = make_float2(q0, q1);
            sk_out[node] = make_float2(k0, k1);
        }
    }
}

// ---------------- CSR build ----------------
__global__ __launch_bounds__(256) void hist_kernel(
    const int* __restrict__ col1, const int* __restrict__ col2,
    int* __restrict__ cnt, int n_nodes, int num_e)
{
    const int sel = blockIdx.x & 1;
    const int bx  = blockIdx.x >> 1;
    const int* col = sel ? col2 : col1;
    const int rb = sel ? n_nodes : 0;
    int e = bx * 256 + threadIdx.x;
    if (e < num_e) atomicAdd(&cnt[rb + col[e]], 1);
}

__global__ __launch_bounds__(256) void scan1_kernel(const int* __restrict__ cnt,
                                                    int* __restrict__ partial, int n)
{
    __shared__ int wsum[4];
    int t = threadIdx.x;
    int i0 = blockIdx.x * 512 + 2 * t;
    int s = ((i0 < n) ? cnt[i0] : 0) + ((i0 + 1 < n) ? cnt[i0 + 1] : 0);
    #pragma unroll
    for (int o = 32; o; o >>= 1) s += __shfl_xor(s, o, 64);
    if ((t & 63) == 0) wsum[t >> 6] = s;
    __syncthreads();
    if (t == 0) partial[blockIdx.x] = wsum[0] + wsum[1] + wsum[2] + wsum[3];
}

__global__ void scan2_kernel(const int* __restrict__ partial, int* __restrict__ pp,
                             int* __restrict__ off, int nch, int noff)
{
    int lane = threadIdx.x;   // 64 threads
    int running = 0;
    for (int base = 0; base < nch; base += 64) {
        int i = base + lane;
        int o = (i < nch) ? partial[i] : 0;
        int v = o;
        #pragma unroll
        for (int d = 1; d < 64; d <<= 1) {
            int u = __shfl_up(v, d, 64);
            if (lane >= d) v += u;
        }
        if (i < nch) pp[i] = running + v - o;
        running += __shfl(v, 63, 64);
    }
    if (lane == 0) off[noff] = running;
}

__global__ __launch_bounds__(256) void scan3_kernel(const int* __restrict__ cnt,
                                                    const int* __restrict__ pp,
                                                    int* __restrict__ off,
                                                    int* __restrict__ cursor, int n)
{
    __shared__ int tmp[256];
    int t = threadIdx.x;
    int i0 = blockIdx.x * 512 + 2 * t;
    int v0 = (i0 < n) ? cnt[i0] : 0;
    int v1 = (i0 + 1 < n) ? cnt[i0 + 1] : 0;
    int pair = v0 + v1;
    tmp[t] = pair;
    __syncthreads();
    for (int d = 1; d < 256; d <<= 1) {
        int x = (t >= d) ? tmp[t - d] : 0;
        __syncthreads();
        tmp[t] += x;
        __syncthreads();
    }
    int excl = tmp[t] - pair + pp[blockIdx.x];
    if (i0 < n)     { off[i0] = excl;          cursor[i0] = excl; }
    if (i0 + 1 < n) { off[i0 + 1] = excl + v0; cursor[i0 + 1] = excl + v0; }
}

// ---------------- fused edge scores + scatter (both relations, XCD-split) ----------------
// 48B CSR record per edge: {src, ex0, ex1, pad, ea[16] bf16}
__global__ __launch_bounds__(256) void edge_score_scatter_kernel(
    const void* __restrict__ ea1p, const void* __restrict__ ea2p,
    const void* __restrict__ We,
    const int* __restrict__ row1, const int* __restrict__ col1,
    const int* __restrict__ row2, const int* __restrict__ col2,
    const float* __restrict__ sq_bp, const float* __restrict__ sk_ap,
    const float* __restrict__ sq_ap, const float* __restrict__ sk_bp,
    const float* __restrict__ cvals, const void* __restrict__ a_attn,
    const int* __restrict__ flagp, int* __restrict__ cursor,
    uint4* __restrict__ payload, int n_nodes, int num_e)
{
    const int f32 = *flagp;
    const int sel = blockIdx.x & 1;
    const int bx  = blockIdx.x >> 1;
    const void* ea = sel ? ea2p : ea1p;
    const int* row = sel ? row2 : row1;
    const int* col = sel ? col2 : col1;
    const float* sq_dst = sel ? sq_ap : sq_bp;
    const float* sk_src = sel ? sk_bp : sk_ap;
    const int rb = sel ? n_nodes : 0;

    __shared__ float We_s[16 * 64];
    __shared__ float a3_s[32];
    for (int i = threadIdx.x; i < 16 * 64; i += 256) We_s[i] = ldf(We, i, f32);
    if (threadIdx.x < 32) a3_s[threadIdx.x] = ldf(a_attn, 96 + threadIdx.x, f32);
    const float c0 = cvals[sel * 2 + 0];
    const float c1 = cvals[sel * 2 + 1];
    __syncthreads();

    const int e0 = bx * 512 + threadIdx.x;
    const int e1 = e0 + 256;
    const bool v1e = (e1 < num_e);
    if (e0 >= num_e) return;

    float er0[16], er1[16];
    load_ea16(ea, (size_t)e0, f32, er0);
    if (v1e) load_ea16(ea, (size_t)e1, f32, er1);
    else {
        #pragma unroll
        for (int c = 0; c < 16; ++c) er1[c] = 0.f;
    }

    float acc00 = 0.f, acc01 = 0.f, acc10 = 0.f, acc11 = 0.f;
    #pragma unroll 1                       // keep rolled: avoids VGPR blowup/spills
    for (int jb = 0; jb < 64; jb += 16) {
        float t0[16], t1[16];
        #pragma unroll
        for (int jj = 0; jj < 16; ++jj) { t0[jj] = 0.f; t1[jj] = 0.f; }
        #pragma unroll
        for (int c = 0; c < 16; ++c) {
            #pragma unroll
            for (int jj = 0; jj < 16; ++jj) {
                float w = We_s[c * 64 + jb + jj];   // uniform broadcast
                t0[jj] += er0[c] * w;
                t1[jj] += er1[c] * w;
            }
        }
        float p0 = 0.f, p1 = 0.f;
        #pragma unroll
        for (int jj = 0; jj < 16; ++jj) {
            float a = a3_s[(jb + jj) & 31];
            p0 += fast_tanh(t0[jj]) * a;
            p1 += fast_tanh(t1[jj]) * a;
        }
        if (jb & 32) { acc01 += p0; acc11 += p1; }
        else         { acc00 += p0; acc10 += p1; }
    }

    {
        int dc = col[e0], s = row[e0];
        float2 sqd = ((const float2*)sq_dst)[dc];
        float2 sks = ((const float2*)sk_src)[s];
        float s0 = fminf(30.f, fmaxf(-30.f, acc00 + sqd.x + sks.x + c0));
        float s1 = fminf(30.f, fmaxf(-30.f, acc01 + sqd.y + sks.y + c1));
        int pos = atomicAdd(&cursor[rb + dc], 1);
        uint4* rec = payload + (size_t)3 * pos;
        unsigned w0 = (unsigned)f2bf_bits(er0[0])  | ((unsigned)f2bf_bits(er0[1])  << 16);
        unsigned w1 = (unsigned)f2bf_bits(er0[2])  | ((unsigned)f2bf_bits(er0[3])  << 16);
        unsigned w2 = (unsigned)f2bf_bits(er0[4])  | ((unsigned)f2bf_bits(er0[5])  << 16);
        unsigned w3 = (unsigned)f2bf_bits(er0[6])  | ((unsigned)f2bf_bits(er0[7])  << 16);
        unsigned w4 = (unsigned)f2bf_bits(er0[8])  | ((unsigned)f2bf_bits(er0[9])  << 16);
        unsigned w5 = (unsigned)f2bf_bits(er0[10]) | ((unsigned)f2bf_bits(er0[11]) << 16);
        unsigned w6 = (unsigned)f2bf_bits(er0[12]) | ((unsigned)f2bf_bits(er0[13]) << 16);
        unsigned w7 = (unsigned)f2bf_bits(er0[14]) | ((unsigned)f2bf_bits(er0[15]) << 16);
        rec[0] = make_uint4((unsigned)s, __float_as_uint(__expf(s0)), __float_as_uint(__expf(s1)), 0u);
        rec[1] = make_uint4(w0, w1, w2, w3);
        rec[2] = make_uint4(w4, w5, w6, w7);
    }
    if (v1e) {
        int dc = col[e1], s = row[e1];
        float2 sqd = ((const float2*)sq_dst)[dc];
        float2 sks = ((const float2*)sk_src)[s];
        float s0 = fminf(30.f, fmaxf(-30.f, acc10 + sqd.x + sks.x + c0));
        float s1 = fminf(30.f, fmaxf(-30.f, acc11 + sqd.y + sks.y + c1));
        int pos = atomicAdd(&cursor[rb + dc], 1);
        uint4* rec = payload + (size_t)3 * pos;
        unsigned w0 = (unsigned)f2bf_bits(er1[0])  | ((unsigned)f2bf_bits(er1[1])  << 16);
        unsigned w1 = (unsigned)f2bf_bits(er1[2])  | ((unsigned)f2bf_bits(er1[3])  << 16);
        unsigned w2 = (unsigned)f2bf_bits(er1[4])  | ((unsigned)f2bf_bits(er1[5])  << 16);
        unsigned w3 = (unsigned)f2bf_bits(er1[6])  | ((unsigned)f2bf_bits(er1[7])  << 16);
        unsigned w4 = (unsigned)f2bf_bits(er1[8])  | ((unsigned)f2bf_bits(er1[9])  << 16);
        unsigned w5 = (unsigned)f2bf_bits(er1[10]) | ((unsigned)f2bf_bits(er1[11]) << 16);
        unsigned w6 = (unsigned)f2bf_bits(er1[12]) | ((unsigned)f2bf_bits(er1[13]) << 16);
        unsigned w7 = (unsigned)f2bf_bits(er1[14]) | ((unsigned)f2bf_bits(er1[15]) << 16);
        rec[0] = make_uint4((unsigned)s, __float_as_uint(__expf(s0)), __float_as_uint(__expf(s1)), 0u);
        rec[1] = make_uint4(w0, w1, w2, w3);
        rec[2] = make_uint4(w4, w5, w6, w7);
    }
}

// ---------------- fused aggregation + output projection (both relations, XCD-split) -----
__global__ __launch_bounds__(256) void agg_final_kernel(
    const uint4* __restrict__ payload, const int* __restrict__ off,
    const unsigned short* __restrict__ v_a, const unsigned short* __restrict__ v_b,
    const float* __restrict__ r_a, const float* __restrict__ r_b,
    const void* __restrict__ Wo_a, const void* __restrict__ Wo_b,
    const void* __restrict__ bo_a, const void* __restrict__ bo_b,
    const float* __restrict__ M1, const float* __restrict__ M2,
    const float* __restrict__ c321, const float* __restrict__ c322,
    const int* __restrict__ flagp, void* __restrict__ out,
    int n_nodes, int nbh)
{
    const int sel = blockIdx.x & 1;                 // 0: rel1 (dst=b), 1: rel2 (dst=a)
    const int bx  = blockIdx.x >> 1;
    const unsigned short* v_src = sel ? v_b : v_a;
    const float* r_src = sel ? r_a : r_b;           // residual of DST type
    const void*  Wo    = sel ? Wo_a : Wo_b;
    const void*  bo    = sel ? bo_a : bo_b;
    const float* M     = sel ? M2 : M1;
    const float* c32   = sel ? c322 : c321;
    const int relbase  = sel ? n_nodes : 0;
    const size_t out_off = sel ? 0 : (size_t)n_nodes * 32;

    const int f32  = *flagp;
    const int lane = threadIdx.x & 63;
    const int wv   = threadIdx.x >> 6;
    const int j    = lane & 31;
    const int half = lane >> 5;
    const int c16  = lane & 15;
    const bool hi  = (lane >= 32);

    __shared__ float stage[4][96];   // per-wave: y[64] | u[32]

    float WoR[32], MR[16];
    const int cb = half * 32;
    #pragma unroll
    for (int cc = 0; cc < 32; ++cc)
        WoR[cc] = ldf(Wo, (size_t)(cb + cc) * 32 + j, f32);
    const int ub = half * 16;
    #pragma unroll
    for (int cc = 0; cc < 16; ++cc) MR[cc] = M[(ub + cc) * 32 + j];
    const float boR  = ldf(bo, j, f32);
    const float c32R = c32[j];

    const int stride = nbh * 4;
    const int iters  = (n_nodes + stride - 1) / stride;
    int d = bx * 4 + wv;

    for (int it = 0; it < iters; ++it, d += stride) {
        const bool valid = (d < n_nodes);
        const int dd  = valid ? d : (n_nodes - 1);
        const int idx = relbase + dd;
        const int b   = __builtin_amdgcn_readfirstlane(off[idx]);
        const int en  = __builtin_amdgcn_readfirstlane(off[idx + 1]);
        const int deg = en - b;

        const float rv = r_src[(size_t)dd * 32 + j];   // early: overlaps edge loop

        float den0 = 0.f, den1 = 0.f, y = 0.f, ua = 0.f;
        int k = b;
        #pragma unroll 1
        for (; k + 8 <= en; k += 8) {
            uint4 m[8];
            #pragma unroll
            for (int q = 0; q < 8; ++q) m[q] = payload[(size_t)3 * (k + q)];
            float ev[8];
            #pragma unroll
            for (int q = 0; q < 8; ++q) {
                const unsigned short* pq = (const unsigned short*)(payload + (size_t)3 * (k + q) + 1);
                ev[q] = __uint_as_float((unsigned)pq[c16] << 16);
            }
            float vv[8];
            #pragma unroll
            for (int q = 0; q < 8; ++q)
                vv[q] = __uint_as_float((unsigned)v_src[(size_t)m[q].x * 64 + lane] << 16);
            #pragma unroll
            for (int q = 0; q < 8; ++q) {
                float e0 = __uint_as_float(m[q].y), e1 = __uint_as_float(m[q].z);
                den0 += e0; den1 += e1;
                float xw = hi ? e1 : e0;
                y  = fmaf(xw, vv[q], y);
                ua = fmaf(xw, ev[q], ua);
            }
        }
        #pragma unroll 1
        for (; k < en; ++k) {
            uint4 mm = payload[(size_t)3 * k];
            const unsigned short* pq = (const unsigned short*)(payload + (size_t)3 * k + 1);
            float evs = __uint_as_float((unsigned)pq[c16] << 16);
            float vvs = __uint_as_float((unsigned)v_src[(size_t)mm.x * 64 + lane] << 16);
            float e0 = __uint_as_float(mm.y), e1 = __uint_as_float(mm.z);
            den0 += e0; den1 += e1;
            float xw = hi ? e1 : e0;
            y  = fmaf(xw, vvs, y);
            ua = fmaf(xw, evs, ua);
        }

        float inv0 = (deg > 0) ? __builtin_amdgcn_rcpf(den0) : 0.f;
        float inv1 = (deg > 0) ? __builtin_amdgcn_rcpf(den1) : 0.f;
        const float invh = hi ? inv1 : inv0;
        y  *= invh;
        ua *= invh;

        // wave-private LDS staging (lockstep wave64 + lgkmcnt drain).
        float* st = stage[wv];
        st[lane] = y;
        if ((lane & 31) < 16) st[64 + half * 16 + c16] = ua;
        __asm__ volatile("s_waitcnt lgkmcnt(0)" ::: "memory");

        float acc = 0.f;
        #pragma unroll
        for (int cc = 0; cc < 32; ++cc)
            acc = fmaf(st[cb + cc], WoR[cc], acc);
        #pragma unroll
        for (int cc = 0; cc < 16; ++cc)
            acc = fmaf(st[64 + ub + cc], MR[cc], acc);

        float other = __shfl(acc, lane ^ 32, 64);
        if (valid && lane < 32) {
            float o = acc + other + boR + rv + ((deg > 0) ? c32R : 0.f);
            stf(out, out_off + (size_t)dd * 32 + j, f32, o);
        }
        __asm__ volatile("" ::: "memory");
        __builtin_amdgcn_wave_barrier();
    }
}

extern "C" void kernel_launch(void* const* d_in, const int* in_sizes, int n_in,
                              void* d_out, int out_size, void* d_ws, size_t ws_size,
                              hipStream_t stream)
{
    const void* x_a   = d_in[0];
    const void* x_b   = d_in[1];
    const void* ea1   = d_in[2];
    const void* ea2   = d_in[3];
    const void* Wq_a  = d_in[4];
    const void* Wk_a  = d_in[5];
    const void* Wv_a  = d_in[6];
    const void* Wq_b  = d_in[7];
    const void* Wk_b  = d_in[8];
    const void* Wv_b  = d_in[9];
    const void* emb_a = d_in[10];
    const void* emb_b = d_in[11];
    const void* rel1  = d_in[12];
    const void* rel2  = d_in[13];
    const void* We    = d_in[14];
    const void* a_at  = d_in[15];
    const void* Wo_a  = d_in[16];
    const void* bo_a  = d_in[17];
    const void* Wo_b  = d_in[18];
    const void* bo_b  = d_in[19];
    const void* Wr_a  = d_in[20];
    const void* Wr_b  = d_in[21];
    const int*  row1  = (const int*)d_in[22];
    const int*  col1  = (const int*)d_in[23];
    const int*  row2  = (const int*)d_in[24];
    const int*  col2  = (const int*)d_in[25];

    const int N = in_sizes[0] / 64;   // nodes per type
    const int E = in_sizes[22];       // edges per relation

    // ---- workspace layout (float units) ----
    float* ws = (float*)d_ws;
    size_t off = 0;
    int*   flag = (int*)ws;        off += 64;
    unsigned short* v_a = (unsigned short*)(ws + off); off += (size_t)N * 32;  // bf16 N x 64
    unsigned short* v_b = (unsigned short*)(ws + off); off += (size_t)N * 32;
    float* r_a  = ws + off;        off += (size_t)N * 32;
    float* r_b  = ws + off;        off += (size_t)N * 32;
    float* sq_a = ws + off;        off += (size_t)N * 2;
    float* sk_a = ws + off;        off += (size_t)N * 2;
    float* sq_b = ws + off;        off += (size_t)N * 2;
    float* sk_b = ws + off;        off += (size_t)N * 2;
    float* cvals = ws + off;       off += 4;
    off = (off + 3) & ~(size_t)3;  // 16B align
    unsigned short* wt = (unsigned short*)(ws + off); off += 28672 / 2;  // 6x4096 + 2x2048 bf16
    float* M1   = ws + off;        off += 1024;
    float* c321 = ws + off;        off += 32;
    float* M2   = ws + off;        off += 1024;
    float* c322 = ws + off;        off += 32;
    int*   cnt    = (int*)(ws + off);  off += (size_t)2 * N;
    int*   offs   = (int*)(ws + off);  off += (size_t)2 * N + 2;
    int*   cursor = (int*)(ws + off);  off += (size_t)2 * N;
    int*   partial = (int*)(ws + off); off += 512;
    int*   pp      = (int*)(ws + off); off += 512;
    off = (off + 3) & ~(size_t)3;     // 16B align for uint4
    uint4* payload = (uint4*)(ws + off); off += (size_t)2 * E * 12;  // 48B records

    const int tiles        = (N + 15) >> 4;
    const int mfma_blocks  = (2 * tiles + 3) / 4;
    const int score_blocks = (E + 511) / 512;
    const int eb_blocks    = (E + 255) / 256;
    const int nch          = (2 * N + 511) / 512;
    const int agg_half     = 2048;                      // blocks per relation

    detect_kernel<<<1, 128, 0, stream>>>((const unsigned short*)a_at, flag);
    hipMemsetAsync(cnt, 0, (size_t)2 * N * sizeof(int), stream);

    prep_small_kernel<<<10, 256, 0, stream>>>(
        Wq_a, Wk_a, Wv_a, Wq_b, Wk_b, Wv_b, Wr_a, Wr_b,
        We, Wo_a, Wo_b, rel1, rel2, a_at, flag,
        wt, M1, c321, M2, c322, cvals);

    node_prep_mfma_kernel<<<mfma_blocks, 256, 0, stream>>>(
        x_a, x_b, wt, emb_a, emb_b, a_at, flag,
        v_a, v_b, r_a, r_b, sq_a, sk_a, sq_b, sk_b, N, tiles);

    hist_kernel<<<2 * eb_blocks, 256, 0, stream>>>(col1, col2, cnt, N, E);
    scan1_kernel<<<nch, 256, 0, stream>>>(cnt, partial, 2 * N);
    scan2_kernel<<<1, 64, 0, stream>>>(partial, pp, offs, nch, 2 * N);
    scan3_kernel<<<nch, 256, 0, stream>>>(cnt, pp, offs, cursor, 2 * N);

    edge_score_scatter_kernel<<<2 * score_blocks, 256, 0, stream>>>(
        ea1, ea2, We, row1, col1, row2, col2,
        sq_b, sk_a, sq_a, sk_b, cvals, a_at, flag,
        cursor, payload, N, E);

    agg_final_kernel<<<2 * agg_half, 256, 0, stream>>>(
        payload, offs, v_a, v_b, r_a, r_b, Wo_a, Wo_b, bo_a, bo_b,
        M1, M2, c321, c322, flag, d_out, N, agg_half);
}